// Round 5
// baseline (180966.052 us; speedup 1.0000x reference)
//
#include <hip/hip_runtime.h>
#include <cstddef>

#define T_STEPS 4096

typedef float    v4f __attribute__((ext_vector_type(4)));
typedef unsigned v4u __attribute__((ext_vector_type(4)));

// ---- ws layout (32-bit word offsets) ----
#define OFF_FLAGS_E 0          // 256 u32, contiguous (16 cache lines)
#define OFF_FLAGS_D 256        // 256 u32
#define OFF_HBUF_E  512        // 3*3072 f32  [slot][ e1 h (2048) | e2 h (1024) ]
#define OFF_HBUF_D  9728       // 3*3072 f32  [slot][ d1 h (1024) | d2 h (2048) ]
#define OFF_XG4     18944      // 3*6144 f32  d2 input gates, mod-3 slots
#define OFF_XGD1    37376      // 3072 f32    d1 constant input gates (incl bih)
#define OFF_PART    40448      // 128*4096 f32 per-wg output partials
#define INIT_WORDS  40448

#define DEV __device__ __forceinline__

DEV float sigm(float v){ return __fdividef(1.f, 1.f + __expf(-v)); }
DEV float tanhx(float v){ float e = __expf(2.f*v); return 1.f - __fdividef(2.f, e + 1.f); }

DEV float wred(float v){
  #pragma unroll
  for (int m = 32; m; m >>= 1) v += __shfl_xor(v, m, 64);
  return v;
}

// scalar agent-scope (bypass non-coherent L1/L2, hit L3)
DEV void  sstore(float* p, float v){ __hip_atomic_store(p, v, __ATOMIC_RELAXED, __HIP_MEMORY_SCOPE_AGENT); }
DEV float sload (const float* p){ return __hip_atomic_load(p, __ATOMIC_RELAXED, __HIP_MEMORY_SCOPE_AGENT); }

// vector scoped loads (sc0 sc1 = bypass L1/L2; data travels via L3)
DEV v4f ldx4s(const float* p){
  v4f a;
  asm volatile("global_load_dwordx4 %0, %1, off sc0 sc1\n\ts_waitcnt vmcnt(0)"
               : "=v"(a) : "v"(p) : "memory");
  return a;
}
DEV void ldx8s(const float* p, v4f* a, v4f* b){
  asm volatile("global_load_dwordx4 %0, %2, off sc0 sc1\n\t"
               "global_load_dwordx4 %1, %2, off offset:16 sc0 sc1\n\t"
               "s_waitcnt vmcnt(0)"
               : "=v"(*a), "=v"(*b) : "v"(p) : "memory");
}
DEV v4u ldx4su(const unsigned* p){
  v4u a;
  asm volatile("global_load_dwordx4 %0, %1, off sc0 sc1\n\ts_waitcnt vmcnt(0)"
               : "=v"(a) : "v"(p) : "memory");
  return a;
}

// pin to ArchVGPR / AGPR (AGPR: the spill-proof second half of the unified file)
#define PINV(x) asm volatile("" : "+v"(x))
#define PINA(x) asm volatile("" : "+a"(x))
// volatile AGPR->VGPR read at use site (volatile so LICM can't hoist the copy)
DEV float aget(float x){
  float t;
  asm volatile("v_accvgpr_read_b32 %0, %1" : "=v"(t) : "a"(x));
  return t;
}

// Distributed 256-wg barrier: contiguous flags (16 lines), dwordx4 poll sweep.
DEV void gbar(unsigned* flags, int wg, unsigned target, int tid){
  __syncthreads();                  // drains vmcnt (scoped data stores reach L3)
  if (tid == 0)
    __hip_atomic_store(&flags[wg], target, __ATOMIC_RELAXED, __HIP_MEMORY_SCOPE_AGENT);
  if (tid < 64){
    const unsigned* fp = flags + tid*4;
    for (;;){
      v4u v = ldx4su(fp);
      unsigned m0 = v.x < v.y ? v.x : v.y;
      unsigned m1 = v.z < v.w ? v.z : v.w;
      unsigned m  = m0 < m1 ? m0 : m1;
      if (__all(m >= target)) break;
      __builtin_amdgcn_s_sleep(2);
    }
  }
  __syncthreads();
}

__global__ void init_kernel(unsigned* ws){
  const int i = blockIdx.x*blockDim.x + threadIdx.x;
  if (i < INIT_WORDS) ws[i] = 0u;
}

// ================= ENCODER: e1 (128 wgs) + e2 lag-1 (128 wgs) =================
__global__ __launch_bounds__(256, 1) __attribute__((amdgpu_waves_per_eu(1,1)))
void enc_kernel(
    const float* __restrict__ x,
    const float* __restrict__ e1_Wih, const float* __restrict__ e1_Whh,
    const float* __restrict__ e1_bih, const float* __restrict__ e1_bhh,
    const float* __restrict__ e2_Wih, const float* __restrict__ e2_Whh,
    const float* __restrict__ e2_bih, const float* __restrict__ e2_bhh,
    float* ws)
{
  const int wg = blockIdx.x, tid = threadIdx.x;
  const int wave = tid >> 6, lane = tid & 63;
  float* hbuf = ws + OFF_HBUF_E;
  unsigned* flags = (unsigned*)ws + OFF_FLAGS_E;

  __shared__ __align__(16) float sh[3072];
  __shared__ float sW[4][12], sBi[4][12], sBh[4][12];

  if (wg < 128){
    // ---- e1 (H=2048). wave owns rows i0..i0+3; lane owns cols lane+64c. ----
    const int gw = wg*4 + wave;          // 0..511
    const int i0 = gw*4;
    float w[3][4][32];                   // 144 VGPR + 240 AGPR, resident
    #pragma unroll
    for (int g=0; g<3; ++g)
      #pragma unroll
      for (int j=0; j<4; ++j)
        #pragma unroll
        for (int c=0; c<32; ++c){
          w[g][j][c] = e1_Whh[(size_t)(g*2048 + i0 + j)*2048 + c*64 + lane];
          if (c < 12) PINV(w[g][j][c]); else PINA(w[g][j][c]);
        }
    if (lane < 12){
      const int g = lane >> 2, j = lane & 3;
      const int row = g*2048 + i0 + j;
      sW[wave][lane]  = e1_Wih[row];
      sBi[wave][lane] = e1_bih[row];
      sBh[wave][lane] = e1_bhh[row];
    }
    __syncthreads();
    for (int s=0; s<=T_STEPS; ++s){
      if (s < T_STEPS){
        const int t = s;
        const float* hp = hbuf + ((t+2)%3)*3072;
        float*       hw = hbuf + (t%3)*3072;
        // stage h (2048 f32) into LDS: 8 floats/thread, scoped dwordx4 pair
        { v4f a, b; ldx8s(hp + tid*8, &a, &b);
          *(v4f*)&sh[tid*8] = a; *(v4f*)&sh[tid*8+4] = b; }
        __syncthreads();
        float hpv[4];
        #pragma unroll
        for (int j=0;j<4;++j) hpv[j] = sh[i0+j];   // LDS broadcast
        const float xt = x[t];
        float acc[3][4];
        #pragma unroll
        for (int g=0;g<3;++g)
          #pragma unroll
          for (int j=0;j<4;++j) acc[g][j] = 0.f;
        #pragma unroll
        for (int cc=0; cc<4; ++cc){
          float hh[8];
          #pragma unroll
          for (int u=0;u<8;++u) hh[u] = sh[(cc*8+u)*64 + lane];
          #pragma unroll
          for (int g=0; g<3; ++g)
            #pragma unroll
            for (int j=0; j<4; ++j)
              #pragma unroll
              for (int u=0;u<8;++u){
                const int c = cc*8+u;
                const float wv = (c < 12) ? w[g][j][c] : aget(w[g][j][c]);
                acc[g][j] = __fmaf_rn(wv, hh[u], acc[g][j]);
              }
        }
        #pragma unroll
        for (int j=0; j<4; ++j){
          const float hr = wred(acc[0][j]);
          const float hz = wred(acc[1][j]);
          const float hn = wred(acc[2][j]);
          const float r = sigm (__fmaf_rn(xt, sW[wave][j],    sBi[wave][j])    + hr + sBh[wave][j]);
          const float z = sigm (__fmaf_rn(xt, sW[wave][4+j],  sBi[wave][4+j])  + hz + sBh[wave][4+j]);
          const float n = tanhx(__fmaf_rn(xt, sW[wave][8+j],  sBi[wave][8+j])  + r*(hn + sBh[wave][8+j]));
          const float hnew = (1.f - z)*n + z*hpv[j];
          if (lane == 0) sstore(hw + i0 + j, hnew);
        }
      }
      gbar(flags, wg, (unsigned)(s+1), tid);
    }
  } else {
    // ---- e2 (H=1024, Kin=2048) lag-1. wave owns rows i0..i0+1. ----
    const int gw = (wg-128)*4 + wave;    // 0..511
    const int i0 = gw*2;
    float wih[3][2][32], whh[3][2][16];  // 96 VGPR + 192 AGPR
    #pragma unroll
    for (int g=0; g<3; ++g)
      #pragma unroll
      for (int j=0; j<2; ++j){
        #pragma unroll
        for (int c=0; c<32; ++c){
          wih[g][j][c] = e2_Wih[(size_t)(g*1024 + i0 + j)*2048 + c*64 + lane];
          if (c < 8) PINV(wih[g][j][c]); else PINA(wih[g][j][c]);
        }
        #pragma unroll
        for (int c=0; c<16; ++c){
          whh[g][j][c] = e2_Whh[(size_t)(g*1024 + i0 + j)*1024 + c*64 + lane];
          if (c < 8) PINV(whh[g][j][c]); else PINA(whh[g][j][c]);
        }
      }
    if (lane < 6){
      const int g = lane >> 1, j = lane & 1;
      const int row = g*1024 + i0 + j;
      sBi[wave][lane] = e2_bih[row];
      sBh[wave][lane] = e2_bhh[row];
    }
    __syncthreads();
    for (int s=0; s<=T_STEPS; ++s){
      if (s >= 1){
        const int t = s-1;
        const float* yp  = hbuf + (t%3)*3072;            // ys1[t]
        const float* hp2 = hbuf + ((t+2)%3)*3072 + 2048; // own h_{t-1}
        float*       hw  = hbuf + (t%3)*3072 + 2048;
        { v4f a, b; ldx8s(yp + tid*8, &a, &b);
          *(v4f*)&sh[tid*8] = a; *(v4f*)&sh[tid*8+4] = b; }
        { v4f c4 = ldx4s(hp2 + tid*4);
          *(v4f*)&sh[2048 + tid*4] = c4; }
        __syncthreads();
        float hpv[2];
        #pragma unroll
        for (int j=0;j<2;++j) hpv[j] = sh[2048 + i0 + j];
        float ar[2]={0,0}, az[2]={0,0}, axn[2]={0,0}, ahn[2]={0,0};
        #pragma unroll
        for (int cc=0; cc<4; ++cc){
          float yy[8];
          #pragma unroll
          for (int u=0;u<8;++u) yy[u] = sh[(cc*8+u)*64 + lane];
          #pragma unroll
          for (int j=0;j<2;++j)
            #pragma unroll
            for (int u=0;u<8;++u){
              const int c = cc*8+u;
              const float w0 = (c < 8) ? wih[0][j][c] : aget(wih[0][j][c]);
              const float w1 = (c < 8) ? wih[1][j][c] : aget(wih[1][j][c]);
              const float w2 = (c < 8) ? wih[2][j][c] : aget(wih[2][j][c]);
              ar[j]  = __fmaf_rn(w0, yy[u], ar[j]);
              az[j]  = __fmaf_rn(w1, yy[u], az[j]);
              axn[j] = __fmaf_rn(w2, yy[u], axn[j]);
            }
        }
        #pragma unroll
        for (int cc=0; cc<2; ++cc){
          float hh[8];
          #pragma unroll
          for (int u=0;u<8;++u) hh[u] = sh[2048 + (cc*8+u)*64 + lane];
          #pragma unroll
          for (int j=0;j<2;++j)
            #pragma unroll
            for (int u=0;u<8;++u){
              const int c = cc*8+u;
              const float w0 = (c < 8) ? whh[0][j][c] : aget(whh[0][j][c]);
              const float w1 = (c < 8) ? whh[1][j][c] : aget(whh[1][j][c]);
              const float w2 = (c < 8) ? whh[2][j][c] : aget(whh[2][j][c]);
              ar[j]  = __fmaf_rn(w0, hh[u], ar[j]);
              az[j]  = __fmaf_rn(w1, hh[u], az[j]);
              ahn[j] = __fmaf_rn(w2, hh[u], ahn[j]);
            }
        }
        #pragma unroll
        for (int j=0; j<2; ++j){
          const float arr = wred(ar[j]), azr = wred(az[j]);
          const float axnr = wred(axn[j]), ahnr = wred(ahn[j]);
          const float r = sigm (arr + sBi[wave][j]   + sBh[wave][j]);
          const float z = sigm (azr + sBi[wave][2+j] + sBh[wave][2+j]);
          const float n = tanhx(axnr + sBi[wave][4+j] + r*(ahnr + sBh[wave][4+j]));
          const float hnew = (1.f - z)*n + z*hpv[j];
          if (lane == 0) sstore(hw + i0 + j, hnew);
        }
      }
      gbar(flags, wg, (unsigned)(s+1), tid);
    }
  }
}

// xgd1[row] = d1_Wih[row,:] . hT + d1_bih[row]  (hT = e2 h at t=4095, slot 0)
__global__ void xgd1_kernel(const float* __restrict__ d1_Wih,
                            const float* __restrict__ d1_bih, float* ws){
  const int gw = blockIdx.x*4 + (threadIdx.x >> 6);  // row 0..3071
  const int lane = threadIdx.x & 63;
  const float* hT = ws + OFF_HBUF_E + 2048;          // slot 0, e2 section
  float a = 0.f;
  #pragma unroll
  for (int c=0;c<16;++c)
    a = __fmaf_rn(d1_Wih[(size_t)gw*1024 + c*64 + lane], hT[c*64 + lane], a);
  a = wred(a);
  if (lane == 0) ws[OFF_XGD1 + gw] = a + d1_bih[gw];
}

// ====== DECODER: d1 (32 wgs) + d2-input GEMV lag-1 (96 wgs) + d2 lag-2 (128 wgs) ======
__global__ __launch_bounds__(256, 1) __attribute__((amdgpu_waves_per_eu(1,1)))
void dec_kernel(
    const float* __restrict__ d1_Whh, const float* __restrict__ d1_bhh,
    const float* __restrict__ d2_Wih, const float* __restrict__ d2_Whh,
    const float* __restrict__ d2_bih, const float* __restrict__ d2_bhh,
    const float* __restrict__ out_W,
    float* ws)
{
  const int wg = blockIdx.x, tid = threadIdx.x;
  const int wave = tid >> 6, lane = tid & 63;
  float* hbuf = ws + OFF_HBUF_D;
  float* xg4  = ws + OFF_XG4;
  unsigned* flags = (unsigned*)ws + OFF_FLAGS_D;
  __shared__ __align__(16) float sh[2048];
  __shared__ float sPS[4];

  if (wg < 32){
    // ---- d1 (H=1024), constant input gates. wave owns rows i0..i0+7. ----
    const int gw = wg*4 + wave;       // 0..127
    const int i0 = gw*8;
    float w[3][8][16];                // 144 VGPR + 240 AGPR
    #pragma unroll
    for (int g=0; g<3; ++g)
      #pragma unroll
      for (int j=0; j<8; ++j)
        #pragma unroll
        for (int c=0; c<16; ++c){
          w[g][j][c] = d1_Whh[(size_t)(g*1024 + i0 + j)*1024 + c*64 + lane];
          if (c < 6) PINV(w[g][j][c]); else PINA(w[g][j][c]);
        }
    float cr[8], cz[8], cxn[8], cbn[8];
    const float* xgc = ws + OFF_XGD1;
    #pragma unroll
    for (int j=0; j<8; ++j){
      cr[j]  = xgc[i0+j]      + d1_bhh[i0+j];
      cz[j]  = xgc[1024+i0+j] + d1_bhh[1024+i0+j];
      cxn[j] = xgc[2048+i0+j];
      cbn[j] = d1_bhh[2048+i0+j];
    }
    for (int s=0; s<=T_STEPS+1; ++s){
      if (s < T_STEPS){
        const int t = s;
        const float* hp = hbuf + ((t+2)%3)*3072;
        float*       hw = hbuf + (t%3)*3072;
        { v4f c4 = ldx4s(hp + tid*4); *(v4f*)&sh[tid*4] = c4; }
        __syncthreads();
        float hpv[8];
        #pragma unroll
        for (int j=0;j<8;++j) hpv[j] = sh[i0+j];
        float a0[8], a1[8], a2[8];
        #pragma unroll
        for (int j=0;j<8;++j){ a0[j]=0.f; a1[j]=0.f; a2[j]=0.f; }
        #pragma unroll
        for (int cc=0; cc<2; ++cc){
          float hh[8];
          #pragma unroll
          for (int u=0;u<8;++u) hh[u] = sh[(cc*8+u)*64 + lane];
          #pragma unroll
          for (int j=0;j<8;++j)
            #pragma unroll
            for (int u=0;u<8;++u){
              const int c = cc*8+u;
              const float w0 = (c < 6) ? w[0][j][c] : aget(w[0][j][c]);
              const float w1 = (c < 6) ? w[1][j][c] : aget(w[1][j][c]);
              const float w2 = (c < 6) ? w[2][j][c] : aget(w[2][j][c]);
              a0[j] = __fmaf_rn(w0, hh[u], a0[j]);
              a1[j] = __fmaf_rn(w1, hh[u], a1[j]);
              a2[j] = __fmaf_rn(w2, hh[u], a2[j]);
            }
        }
        #pragma unroll
        for (int j=0; j<8; ++j){
          const float hr = wred(a0[j]), hz = wred(a1[j]), hn = wred(a2[j]);
          const float r = sigm (cr[j] + hr);
          const float z = sigm (cz[j] + hz);
          const float n = tanhx(cxn[j] + r*(hn + cbn[j]));
          const float hnew = (1.f - z)*n + z*hpv[j];
          if (lane == 0) sstore(hw + i0 + j, hnew);
        }
      }
      gbar(flags, wg, (unsigned)(s+1), tid);
    }
  } else if (wg < 128){
    // ---- d2 input GEMV: xg4[t] = d2_Wih @ ys2[t] + bih, lag-1. wave owns 16 rows. ----
    const int gw = (wg-32)*4 + wave;   // 0..383
    const int r0 = gw*16;
    float w[16][16];                   // 96 VGPR + 160 AGPR
    #pragma unroll
    for (int r=0; r<16; ++r)
      #pragma unroll
      for (int c=0; c<16; ++c){
        w[r][c] = d2_Wih[(size_t)(r0 + r)*1024 + c*64 + lane];
        if (c < 6) PINV(w[r][c]); else PINA(w[r][c]);
      }
    float bv[16];
    #pragma unroll
    for (int r=0; r<16; ++r) bv[r] = d2_bih[r0+r];
    for (int s=0; s<=T_STEPS+1; ++s){
      if (s >= 1 && s <= T_STEPS){
        const int t = s-1;
        const float* yp = hbuf + (t%3)*3072;   // ys2[t] (d1 section)
        float*       xw = xg4 + (t%3)*6144;
        { v4f c4 = ldx4s(yp + tid*4); *(v4f*)&sh[tid*4] = c4; }
        __syncthreads();
        float acc[16];
        #pragma unroll
        for (int r=0;r<16;++r) acc[r]=0.f;
        #pragma unroll
        for (int cc=0; cc<2; ++cc){
          float yy[8];
          #pragma unroll
          for (int u=0;u<8;++u) yy[u] = sh[(cc*8+u)*64 + lane];
          #pragma unroll
          for (int r=0;r<16;++r)
            #pragma unroll
            for (int u=0;u<8;++u){
              const int c = cc*8+u;
              const float wv = (c < 6) ? w[r][c] : aget(w[r][c]);
              acc[r] = __fmaf_rn(wv, yy[u], acc[r]);
            }
        }
        #pragma unroll
        for (int r=0; r<16; ++r){
          const float a = wred(acc[r]);
          if (lane == r) sstore(xw + r0 + r, a + bv[r]);
        }
      }
      gbar(flags, wg, (unsigned)(s+1), tid);
    }
  } else {
    // ---- d2 (H=2048) lag-2, fused output projection. wave owns rows i0..i0+3. ----
    const int gw = (wg-128)*4 + wave;  // 0..511
    const int i0 = gw*4;
    float w[3][4][32];                 // 144 VGPR + 240 AGPR
    #pragma unroll
    for (int g=0; g<3; ++g)
      #pragma unroll
      for (int j=0; j<4; ++j)
        #pragma unroll
        for (int c=0; c<32; ++c){
          w[g][j][c] = d2_Whh[(size_t)(g*2048 + i0 + j)*2048 + c*64 + lane];
          if (c < 12) PINV(w[g][j][c]); else PINA(w[g][j][c]);
        }
    float bh[3][4];
    #pragma unroll
    for (int g=0; g<3; ++g)
      #pragma unroll
      for (int j=0; j<4; ++j) bh[g][j] = d2_bhh[g*2048 + i0 + j];
    float ow[4];
    #pragma unroll
    for (int j=0; j<4; ++j) ow[j] = out_W[i0+j];
    float* part = ws + OFF_PART + (size_t)(wg-128)*4096;
    for (int s=0; s<=T_STEPS+1; ++s){
      if (s >= 2){
        const int t = s-2;
        const float* hp  = hbuf + ((t+2)%3)*3072 + 1024;
        float*       hw  = hbuf + (t%3)*3072 + 1024;
        const float* xgp = xg4 + (t%3)*6144;
        { v4f a, b; ldx8s(hp + tid*8, &a, &b);
          *(v4f*)&sh[tid*8] = a; *(v4f*)&sh[tid*8+4] = b; }
        __syncthreads();
        float hpv[4], xr4[4], xz4[4], xn4[4];
        #pragma unroll
        for (int j=0;j<4;++j){
          hpv[j] = sh[i0+j];
          xr4[j] = sload(xgp + i0 + j);          // wave-uniform address
          xz4[j] = sload(xgp + 2048 + i0 + j);
          xn4[j] = sload(xgp + 4096 + i0 + j);
        }
        float a0[4], a1[4], a2[4];
        #pragma unroll
        for (int j=0;j<4;++j){ a0[j]=0.f; a1[j]=0.f; a2[j]=0.f; }
        #pragma unroll
        for (int cc=0; cc<4; ++cc){
          float hh[8];
          #pragma unroll
          for (int u=0;u<8;++u) hh[u] = sh[(cc*8+u)*64 + lane];
          #pragma unroll
          for (int j=0;j<4;++j)
            #pragma unroll
            for (int u=0;u<8;++u){
              const int c = cc*8+u;
              const float w0 = (c < 12) ? w[0][j][c] : aget(w[0][j][c]);
              const float w1 = (c < 12) ? w[1][j][c] : aget(w[1][j][c]);
              const float w2 = (c < 12) ? w[2][j][c] : aget(w[2][j][c]);
              a0[j] = __fmaf_rn(w0, hh[u], a0[j]);
              a1[j] = __fmaf_rn(w1, hh[u], a1[j]);
              a2[j] = __fmaf_rn(w2, hh[u], a2[j]);
            }
        }
        float op = 0.f;
        #pragma unroll
        for (int j=0; j<4; ++j){
          const float hr = wred(a0[j]), hz = wred(a1[j]), hn = wred(a2[j]);
          const float r = sigm (xr4[j] + hr + bh[0][j]);
          const float z = sigm (xz4[j] + hz + bh[1][j]);
          const float n = tanhx(xn4[j] + r*(hn + bh[2][j]));
          const float hnew = (1.f - z)*n + z*hpv[j];
          if (lane == 0) sstore(hw + i0 + j, hnew);
          op = __fmaf_rn(hnew, ow[j], op);
        }
        if (lane == 0) sPS[wave] = op;
        __syncthreads();
        if (tid == 0) part[t] = sPS[0]+sPS[1]+sPS[2]+sPS[3];
        __syncthreads();
      }
      gbar(flags, wg, (unsigned)(s+1), tid);
    }
  }
}

__global__ void out_kernel(const float* __restrict__ out_b,
                           const float* __restrict__ ws, float* __restrict__ out){
  const int t = blockIdx.x*256 + threadIdx.x;
  float a = 0.f;
  for (int b=0; b<128; ++b) a += ws[OFF_PART + (size_t)b*4096 + t];
  out[t] = a + out_b[0];
}

extern "C" void kernel_launch(void* const* d_in, const int* in_sizes, int n_in,
                              void* d_out, int out_size, void* d_ws, size_t ws_size,
                              hipStream_t stream){
  const float* x       = (const float*)d_in[0];
  const float* e1_Wih  = (const float*)d_in[1];
  const float* e1_Whh  = (const float*)d_in[2];
  const float* e1_bih  = (const float*)d_in[3];
  const float* e1_bhh  = (const float*)d_in[4];
  const float* e2_Wih  = (const float*)d_in[5];
  const float* e2_Whh  = (const float*)d_in[6];
  const float* e2_bih  = (const float*)d_in[7];
  const float* e2_bhh  = (const float*)d_in[8];
  const float* d1_Wih  = (const float*)d_in[9];
  const float* d1_Whh  = (const float*)d_in[10];
  const float* d1_bih  = (const float*)d_in[11];
  const float* d1_bhh  = (const float*)d_in[12];
  const float* d2_Wih  = (const float*)d_in[13];
  const float* d2_Whh  = (const float*)d_in[14];
  const float* d2_bih  = (const float*)d_in[15];
  const float* d2_bhh  = (const float*)d_in[16];
  const float* out_W   = (const float*)d_in[17];
  const float* out_b   = (const float*)d_in[18];
  float* ws  = (float*)d_ws;
  float* out = (float*)d_out;

  hipLaunchKernelGGL(init_kernel, dim3((INIT_WORDS+255)/256), dim3(256), 0, stream,
                     (unsigned*)d_ws);
  hipLaunchKernelGGL(enc_kernel, dim3(256), dim3(256), 0, stream,
                     x, e1_Wih, e1_Whh, e1_bih, e1_bhh,
                     e2_Wih, e2_Whh, e2_bih, e2_bhh, ws);
  hipLaunchKernelGGL(xgd1_kernel, dim3(768), dim3(256), 0, stream,
                     d1_Wih, d1_bih, ws);
  hipLaunchKernelGGL(dec_kernel, dim3(256), dim3(256), 0, stream,
                     d1_Whh, d1_bhh, d2_Wih, d2_Whh, d2_bih, d2_bhh, out_W, ws);
  hipLaunchKernelGGL(out_kernel, dim3(16), dim3(256), 0, stream,
                     out_b, ws, out);
}

// Round 6
// 63034.424 us; speedup vs baseline: 2.8709x; 2.8709x over previous
//
#include <hip/hip_runtime.h>
#include <cstddef>

#define T_STEPS 4096

typedef float    v2f __attribute__((ext_vector_type(2)));
typedef float    v4f __attribute__((ext_vector_type(4)));
typedef unsigned v4u __attribute__((ext_vector_type(4)));

// ---- ws layout (32-bit word offsets) ----
#define OFF_FLAGS_E 0          // 256 u32, contiguous (16 cache lines)
#define OFF_FLAGS_D 256        // 256 u32
#define OFF_HBUF_E  512        // 3*3072 f32  [slot][ e1 h (2048) | e2 h (1024) ]
#define OFF_HBUF_D  9728       // 3*3072 f32  [slot][ d1 h (1024) | d2 h (2048) ]
#define OFF_XG4     18944      // 3*6144 f32  d2 input gates, mod-3 slots
#define OFF_XGD1    37376      // 3072 f32    d1 constant input gates (incl bih)
#define OFF_PART    40448      // 128*4096 f32 per-wg output partials
#define INIT_WORDS  40448

#define DEV __device__ __forceinline__

DEV float sigm(float v){ return __fdividef(1.f, 1.f + __expf(-v)); }
DEV float tanhx(float v){ float e = __expf(2.f*v); return 1.f - __fdividef(2.f, e + 1.f); }

DEV float wred(float v){
  #pragma unroll
  for (int m = 32; m; m >>= 1) v += __shfl_xor(v, m, 64);
  return v;
}

// scalar agent-scope (bypass non-coherent L1/L2, data via L3)
DEV void  sstore(float* p, float v){ __hip_atomic_store(p, v, __ATOMIC_RELAXED, __HIP_MEMORY_SCOPE_AGENT); }
DEV float sload (const float* p){ return __hip_atomic_load(p, __ATOMIC_RELAXED, __HIP_MEMORY_SCOPE_AGENT); }

// vector scoped loads (sc0 sc1 = bypass L1/L2)
DEV v4f ldx4s(const float* p){
  v4f a;
  asm volatile("global_load_dwordx4 %0, %1, off sc0 sc1\n\ts_waitcnt vmcnt(0)"
               : "=v"(a) : "v"(p) : "memory");
  return a;
}
DEV v2f ldx2s(const float* p){
  v2f a;
  asm volatile("global_load_dwordx2 %0, %1, off sc0 sc1\n\ts_waitcnt vmcnt(0)"
               : "=v"(a) : "v"(p) : "memory");
  return a;
}
DEV v4u ldx4su(const unsigned* p){
  v4u a;
  asm volatile("global_load_dwordx4 %0, %1, off sc0 sc1\n\ts_waitcnt vmcnt(0)"
               : "=v"(a) : "v"(p) : "memory");
  return a;
}

// force value into a VGPR at init (load can't be sunk into the loop)
#define PINV(x) asm volatile("" : "+v"(x))

// Distributed 256-wg barrier: contiguous flags, wave 0 polls with dwordx4 sweep.
DEV void gbar(unsigned* flags, int wg, unsigned target, int tid){
  __syncthreads();                  // drains vmcnt (scoped stores reach L3)
  if (tid == 0)
    __hip_atomic_store(&flags[wg], target, __ATOMIC_RELAXED, __HIP_MEMORY_SCOPE_AGENT);
  if (tid < 64){
    const unsigned* fp = flags + tid*4;
    for (;;){
      v4u v = ldx4su(fp);
      unsigned m0 = v.x < v.y ? v.x : v.y;
      unsigned m1 = v.z < v.w ? v.z : v.w;
      unsigned m  = m0 < m1 ? m0 : m1;
      if (__all(m >= target)) break;
      __builtin_amdgcn_s_sleep(2);
    }
  }
  __syncthreads();
}

__global__ void init_kernel(unsigned* ws){
  const int i = blockIdx.x*blockDim.x + threadIdx.x;
  if (i < INIT_WORDS) ws[i] = 0u;
}

// ============ ENCODER: e1 (128 wgs, 2 rows/wave) + e2 lag-1 (128 wgs, 1 row/wave) ============
__global__ __launch_bounds__(512, 2) void enc_kernel(
    const float* __restrict__ x,
    const float* __restrict__ e1_Wih, const float* __restrict__ e1_Whh,
    const float* __restrict__ e1_bih, const float* __restrict__ e1_bhh,
    const float* __restrict__ e2_Wih, const float* __restrict__ e2_Whh,
    const float* __restrict__ e2_bih, const float* __restrict__ e2_bhh,
    float* ws)
{
  const int wg = blockIdx.x, tid = threadIdx.x;
  const int wave = tid >> 6, lane = tid & 63;
  float* hbuf = ws + OFF_HBUF_E;
  unsigned* flags = (unsigned*)ws + OFF_FLAGS_E;

  __shared__ __align__(16) float sh[3072];
  __shared__ float sW[8][6], sBi[8][6], sBh[8][6];

  if (wg < 128){
    // ---- e1 (H=2048, K=2048). wave owns rows i0,i0+1; lane owns cols lane+64c. ----
    const int gw = wg*8 + wave;          // 0..1023
    const int i0 = gw*2;
    float w[3][2][32];                   // 192 VGPRs
    #pragma unroll
    for (int g=0; g<3; ++g)
      #pragma unroll
      for (int j=0; j<2; ++j)
        #pragma unroll
        for (int c=0; c<32; ++c){
          w[g][j][c] = e1_Whh[(size_t)(g*2048 + i0 + j)*2048 + c*64 + lane];
          PINV(w[g][j][c]);
        }
    if (lane < 6){
      const int g = lane >> 1, j = lane & 1;
      const int row = g*2048 + i0 + j;
      sW[wave][lane]  = e1_Wih[row];
      sBi[wave][lane] = e1_bih[row];
      sBh[wave][lane] = e1_bhh[row];
    }
    __syncthreads();
    for (int s=0; s<=T_STEPS; ++s){
      if (s < T_STEPS){
        const int t = s;
        const float* hp = hbuf + ((t+2)%3)*3072;
        float*       hw = hbuf + (t%3)*3072;
        { v4f a = ldx4s(hp + tid*4); *(v4f*)&sh[tid*4] = a; }   // 2048 f32
        __syncthreads();
        float hpv[2];
        #pragma unroll
        for (int j=0;j<2;++j) hpv[j] = sh[i0+j];
        const float xt = x[t];
        float acc[3][2];
        #pragma unroll
        for (int g=0;g<3;++g){ acc[g][0]=0.f; acc[g][1]=0.f; }
        #pragma unroll
        for (int cc=0; cc<4; ++cc){
          float hh[8];
          #pragma unroll
          for (int u=0;u<8;++u) hh[u] = sh[(cc*8+u)*64 + lane];
          #pragma unroll
          for (int g=0; g<3; ++g)
            #pragma unroll
            for (int j=0; j<2; ++j)
              #pragma unroll
              for (int u=0;u<8;++u)
                acc[g][j] = __fmaf_rn(w[g][j][cc*8+u], hh[u], acc[g][j]);
        }
        #pragma unroll
        for (int j=0; j<2; ++j){
          const float hr = wred(acc[0][j]);
          const float hz = wred(acc[1][j]);
          const float hn = wred(acc[2][j]);
          const float r = sigm (__fmaf_rn(xt, sW[wave][j],   sBi[wave][j])   + hr + sBh[wave][j]);
          const float z = sigm (__fmaf_rn(xt, sW[wave][2+j], sBi[wave][2+j]) + hz + sBh[wave][2+j]);
          const float n = tanhx(__fmaf_rn(xt, sW[wave][4+j], sBi[wave][4+j]) + r*(hn + sBh[wave][4+j]));
          const float hnew = (1.f - z)*n + z*hpv[j];
          if (lane == 0) sstore(hw + i0 + j, hnew);
        }
      }
      gbar(flags, wg, (unsigned)(s+1), tid);
    }
  } else {
    // ---- e2 (H=1024, Kin=2048, Khh=1024) lag-1. wave owns row i0. ----
    const int gw = (wg-128)*8 + wave;    // 0..1023
    const int i0 = gw;
    float wih[3][32], whh[3][16];        // 96 + 48 = 144 VGPRs
    #pragma unroll
    for (int g=0; g<3; ++g){
      #pragma unroll
      for (int c=0; c<32; ++c){
        wih[g][c] = e2_Wih[(size_t)(g*1024 + i0)*2048 + c*64 + lane];
        PINV(wih[g][c]);
      }
      #pragma unroll
      for (int c=0; c<16; ++c){
        whh[g][c] = e2_Whh[(size_t)(g*1024 + i0)*1024 + c*64 + lane];
        PINV(whh[g][c]);
      }
    }
    if (lane < 3){
      const int row = lane*1024 + i0;
      sBi[wave][lane] = e2_bih[row];
      sBh[wave][lane] = e2_bhh[row];
    }
    __syncthreads();
    for (int s=0; s<=T_STEPS; ++s){
      if (s >= 1){
        const int t = s-1;
        const float* yp  = hbuf + (t%3)*3072;            // ys1[t]
        const float* hp2 = hbuf + ((t+2)%3)*3072 + 2048; // own h_{t-1}
        float*       hw  = hbuf + (t%3)*3072 + 2048;
        { v4f a = ldx4s(yp + tid*4);  *(v4f*)&sh[tid*4] = a; }        // 2048
        { v2f b = ldx2s(hp2 + tid*2); *(v2f*)&sh[2048 + tid*2] = b; } // 1024
        __syncthreads();
        const float hpv = sh[2048 + i0];
        float ar=0.f, az=0.f, axn=0.f, ahn=0.f;
        #pragma unroll
        for (int cc=0; cc<4; ++cc){
          float yy[8];
          #pragma unroll
          for (int u=0;u<8;++u) yy[u] = sh[(cc*8+u)*64 + lane];
          #pragma unroll
          for (int u=0;u<8;++u){
            ar  = __fmaf_rn(wih[0][cc*8+u], yy[u], ar);
            az  = __fmaf_rn(wih[1][cc*8+u], yy[u], az);
            axn = __fmaf_rn(wih[2][cc*8+u], yy[u], axn);
          }
        }
        #pragma unroll
        for (int cc=0; cc<2; ++cc){
          float hh[8];
          #pragma unroll
          for (int u=0;u<8;++u) hh[u] = sh[2048 + (cc*8+u)*64 + lane];
          #pragma unroll
          for (int u=0;u<8;++u){
            ar  = __fmaf_rn(whh[0][cc*8+u], hh[u], ar);
            az  = __fmaf_rn(whh[1][cc*8+u], hh[u], az);
            ahn = __fmaf_rn(whh[2][cc*8+u], hh[u], ahn);
          }
        }
        const float arr = wred(ar), azr = wred(az), axnr = wred(axn), ahnr = wred(ahn);
        const float r = sigm (arr + sBi[wave][0] + sBh[wave][0]);
        const float z = sigm (azr + sBi[wave][1] + sBh[wave][1]);
        const float n = tanhx(axnr + sBi[wave][2] + r*(ahnr + sBh[wave][2]));
        const float hnew = (1.f - z)*n + z*hpv;
        if (lane == 0) sstore(hw + i0, hnew);
      }
      gbar(flags, wg, (unsigned)(s+1), tid);
    }
  }
}

// xgd1[row] = d1_Wih[row,:] . hT + d1_bih[row]  (hT = e2 h at t=4095, slot 0)
__global__ void xgd1_kernel(const float* __restrict__ d1_Wih,
                            const float* __restrict__ d1_bih, float* ws){
  const int gw = blockIdx.x*4 + (threadIdx.x >> 6);  // row 0..3071
  const int lane = threadIdx.x & 63;
  const float* hT = ws + OFF_HBUF_E + 2048;          // slot 0, e2 section
  float a = 0.f;
  #pragma unroll
  for (int c=0;c<16;++c)
    a = __fmaf_rn(d1_Wih[(size_t)gw*1024 + c*64 + lane], hT[c*64 + lane], a);
  a = wred(a);
  if (lane == 0) ws[OFF_XGD1 + gw] = a + d1_bih[gw];
}

// ====== DECODER: d1 (64 wgs, 2 rows/wave) + d2-gemv lag-1 (64 wgs, 12 rows/wave)
//                + d2 lag-2 (128 wgs, 2 rows/wave) ======
__global__ __launch_bounds__(512, 2) void dec_kernel(
    const float* __restrict__ d1_Whh, const float* __restrict__ d1_bhh,
    const float* __restrict__ d2_Wih, const float* __restrict__ d2_Whh,
    const float* __restrict__ d2_bih, const float* __restrict__ d2_bhh,
    const float* __restrict__ out_W,
    float* ws)
{
  const int wg = blockIdx.x, tid = threadIdx.x;
  const int wave = tid >> 6, lane = tid & 63;
  float* hbuf = ws + OFF_HBUF_D;
  float* xg4  = ws + OFF_XG4;
  unsigned* flags = (unsigned*)ws + OFF_FLAGS_D;
  __shared__ __align__(16) float sh[2048];
  __shared__ float sPS[8];

  if (wg < 64){
    // ---- d1 (H=1024, K=1024), constant input gates. wave owns rows i0,i0+1. ----
    const int gw = wg*8 + wave;       // 0..511
    const int i0 = gw*2;
    float w[3][2][16];                // 96 VGPRs
    #pragma unroll
    for (int g=0; g<3; ++g)
      #pragma unroll
      for (int j=0; j<2; ++j)
        #pragma unroll
        for (int c=0; c<16; ++c){
          w[g][j][c] = d1_Whh[(size_t)(g*1024 + i0 + j)*1024 + c*64 + lane];
          PINV(w[g][j][c]);
        }
    float cr[2], cz[2], cxn[2], cbn[2];
    const float* xgc = ws + OFF_XGD1;
    #pragma unroll
    for (int j=0; j<2; ++j){
      cr[j]  = xgc[i0+j]      + d1_bhh[i0+j];
      cz[j]  = xgc[1024+i0+j] + d1_bhh[1024+i0+j];
      cxn[j] = xgc[2048+i0+j];
      cbn[j] = d1_bhh[2048+i0+j];
    }
    for (int s=0; s<=T_STEPS+1; ++s){
      if (s < T_STEPS){
        const int t = s;
        const float* hp = hbuf + ((t+2)%3)*3072;
        float*       hw = hbuf + (t%3)*3072;
        { v2f a = ldx2s(hp + tid*2); *(v2f*)&sh[tid*2] = a; }  // 1024
        __syncthreads();
        float hpv[2];
        #pragma unroll
        for (int j=0;j<2;++j) hpv[j] = sh[i0+j];
        float a0[2]={0,0}, a1[2]={0,0}, a2[2]={0,0};
        #pragma unroll
        for (int cc=0; cc<2; ++cc){
          float hh[8];
          #pragma unroll
          for (int u=0;u<8;++u) hh[u] = sh[(cc*8+u)*64 + lane];
          #pragma unroll
          for (int j=0;j<2;++j)
            #pragma unroll
            for (int u=0;u<8;++u){
              a0[j] = __fmaf_rn(w[0][j][cc*8+u], hh[u], a0[j]);
              a1[j] = __fmaf_rn(w[1][j][cc*8+u], hh[u], a1[j]);
              a2[j] = __fmaf_rn(w[2][j][cc*8+u], hh[u], a2[j]);
            }
        }
        #pragma unroll
        for (int j=0; j<2; ++j){
          const float hr = wred(a0[j]), hz = wred(a1[j]), hn = wred(a2[j]);
          const float r = sigm (cr[j] + hr);
          const float z = sigm (cz[j] + hz);
          const float n = tanhx(cxn[j] + r*(hn + cbn[j]));
          const float hnew = (1.f - z)*n + z*hpv[j];
          if (lane == 0) sstore(hw + i0 + j, hnew);
        }
        __syncthreads();   // keep sh stable until all waves done reading
      }
      gbar(flags, wg, (unsigned)(s+1), tid);
    }
  } else if (wg < 128){
    // ---- d2 input GEMV: xg4[t] = d2_Wih @ ys2[t] + bih, lag-1. wave owns 12 rows. ----
    const int gw = (wg-64)*8 + wave;   // 0..511
    const int r0 = gw*12;
    float w[12][16];                   // 192 VGPRs
    #pragma unroll
    for (int r=0; r<12; ++r)
      #pragma unroll
      for (int c=0; c<16; ++c){
        w[r][c] = d2_Wih[(size_t)(r0 + r)*1024 + c*64 + lane];
        PINV(w[r][c]);
      }
    float bv[12];
    #pragma unroll
    for (int r=0; r<12; ++r) bv[r] = d2_bih[r0+r];
    for (int s=0; s<=T_STEPS+1; ++s){
      if (s >= 1 && s <= T_STEPS){
        const int t = s-1;
        const float* yp = hbuf + (t%3)*3072;   // ys2[t] (d1 section)
        float*       xw = xg4 + (t%3)*6144;
        { v2f a = ldx2s(yp + tid*2); *(v2f*)&sh[tid*2] = a; }  // 1024
        __syncthreads();
        float acc[12];
        #pragma unroll
        for (int r=0;r<12;++r) acc[r]=0.f;
        #pragma unroll
        for (int cc=0; cc<4; ++cc){
          float yy[4];
          #pragma unroll
          for (int u=0;u<4;++u) yy[u] = sh[(cc*4+u)*64 + lane];
          #pragma unroll
          for (int r=0;r<12;++r)
            #pragma unroll
            for (int u=0;u<4;++u)
              acc[r] = __fmaf_rn(w[r][cc*4+u], yy[u], acc[r]);
        }
        #pragma unroll
        for (int r=0; r<12; ++r){
          const float a = wred(acc[r]);
          if (lane == r) sstore(xw + r0 + r, a + bv[r]);
        }
        __syncthreads();
      }
      gbar(flags, wg, (unsigned)(s+1), tid);
    }
  } else {
    // ---- d2 (H=2048, K=2048) lag-2, fused output projection. wave owns rows i0,i0+1. ----
    const int gw = (wg-128)*8 + wave;  // 0..1023
    const int i0 = gw*2;
    float w[3][2][32];                 // 192 VGPRs
    #pragma unroll
    for (int g=0; g<3; ++g)
      #pragma unroll
      for (int j=0; j<2; ++j)
        #pragma unroll
        for (int c=0; c<32; ++c){
          w[g][j][c] = d2_Whh[(size_t)(g*2048 + i0 + j)*2048 + c*64 + lane];
          PINV(w[g][j][c]);
        }
    float bh[3][2];
    #pragma unroll
    for (int g=0; g<3; ++g)
      #pragma unroll
      for (int j=0; j<2; ++j) bh[g][j] = d2_bhh[g*2048 + i0 + j];
    float ow[2];
    #pragma unroll
    for (int j=0; j<2; ++j) ow[j] = out_W[i0+j];
    float* part = ws + OFF_PART + (size_t)(wg-128)*4096;
    for (int s=0; s<=T_STEPS+1; ++s){
      if (s >= 2){
        const int t = s-2;
        const float* hp  = hbuf + ((t+2)%3)*3072 + 1024;
        float*       hw  = hbuf + (t%3)*3072 + 1024;
        const float* xgp = xg4 + (t%3)*6144;
        { v4f a = ldx4s(hp + tid*4); *(v4f*)&sh[tid*4] = a; }  // 2048
        __syncthreads();
        float hpv[2], xr4[2], xz4[2], xn4[2];
        #pragma unroll
        for (int j=0;j<2;++j){
          hpv[j] = sh[i0+j];
          xr4[j] = sload(xgp + i0 + j);
          xz4[j] = sload(xgp + 2048 + i0 + j);
          xn4[j] = sload(xgp + 4096 + i0 + j);
        }
        float a0[2]={0,0}, a1[2]={0,0}, a2[2]={0,0};
        #pragma unroll
        for (int cc=0; cc<4; ++cc){
          float hh[8];
          #pragma unroll
          for (int u=0;u<8;++u) hh[u] = sh[(cc*8+u)*64 + lane];
          #pragma unroll
          for (int j=0;j<2;++j)
            #pragma unroll
            for (int u=0;u<8;++u){
              a0[j] = __fmaf_rn(w[0][j][cc*8+u], hh[u], a0[j]);
              a1[j] = __fmaf_rn(w[1][j][cc*8+u], hh[u], a1[j]);
              a2[j] = __fmaf_rn(w[2][j][cc*8+u], hh[u], a2[j]);
            }
        }
        float op = 0.f;
        #pragma unroll
        for (int j=0; j<2; ++j){
          const float hr = wred(a0[j]), hz = wred(a1[j]), hn = wred(a2[j]);
          const float r = sigm (xr4[j] + hr + bh[0][j]);
          const float z = sigm (xz4[j] + hz + bh[1][j]);
          const float n = tanhx(xn4[j] + r*(hn + bh[2][j]));
          const float hnew = (1.f - z)*n + z*hpv[j];
          if (lane == 0) sstore(hw + i0 + j, hnew);
          op = __fmaf_rn(hnew, ow[j], op);
        }
        if (lane == 0) sPS[wave] = op;
        __syncthreads();
        if (tid == 0){
          float ps = 0.f;
          #pragma unroll
          for (int v=0; v<8; ++v) ps += sPS[v];
          part[t] = ps;
        }
        __syncthreads();
      }
      gbar(flags, wg, (unsigned)(s+1), tid);
    }
  }
}

__global__ void out_kernel(const float* __restrict__ out_b,
                           const float* __restrict__ ws, float* __restrict__ out){
  const int t = blockIdx.x*256 + threadIdx.x;
  float a = 0.f;
  for (int b=0; b<128; ++b) a += ws[OFF_PART + (size_t)b*4096 + t];
  out[t] = a + out_b[0];
}

extern "C" void kernel_launch(void* const* d_in, const int* in_sizes, int n_in,
                              void* d_out, int out_size, void* d_ws, size_t ws_size,
                              hipStream_t stream){
  const float* x       = (const float*)d_in[0];
  const float* e1_Wih  = (const float*)d_in[1];
  const float* e1_Whh  = (const float*)d_in[2];
  const float* e1_bih  = (const float*)d_in[3];
  const float* e1_bhh  = (const float*)d_in[4];
  const float* e2_Wih  = (const float*)d_in[5];
  const float* e2_Whh  = (const float*)d_in[6];
  const float* e2_bih  = (const float*)d_in[7];
  const float* e2_bhh  = (const float*)d_in[8];
  const float* d1_Wih  = (const float*)d_in[9];
  const float* d1_Whh  = (const float*)d_in[10];
  const float* d1_bih  = (const float*)d_in[11];
  const float* d1_bhh  = (const float*)d_in[12];
  const float* d2_Wih  = (const float*)d_in[13];
  const float* d2_Whh  = (const float*)d_in[14];
  const float* d2_bih  = (const float*)d_in[15];
  const float* d2_bhh  = (const float*)d_in[16];
  const float* out_W   = (const float*)d_in[17];
  const float* out_b   = (const float*)d_in[18];
  float* ws  = (float*)d_ws;
  float* out = (float*)d_out;

  hipLaunchKernelGGL(init_kernel, dim3((INIT_WORDS+255)/256), dim3(256), 0, stream,
                     (unsigned*)d_ws);
  hipLaunchKernelGGL(enc_kernel, dim3(256), dim3(512), 0, stream,
                     x, e1_Wih, e1_Whh, e1_bih, e1_bhh,
                     e2_Wih, e2_Whh, e2_bih, e2_bhh, ws);
  hipLaunchKernelGGL(xgd1_kernel, dim3(768), dim3(256), 0, stream,
                     d1_Wih, d1_bih, ws);
  hipLaunchKernelGGL(dec_kernel, dim3(256), dim3(512), 0, stream,
                     d1_Whh, d1_bhh, d2_Wih, d2_Whh, d2_bih, d2_bhh, out_W, ws);
  hipLaunchKernelGGL(out_kernel, dim3(16), dim3(256), 0, stream,
                     out_b, ws, out);
}

// Round 7
// 62512.457 us; speedup vs baseline: 2.8949x; 1.0083x over previous
//
#include <hip/hip_runtime.h>
#include <cstddef>

#define T_STEPS 4096

typedef float    v2f __attribute__((ext_vector_type(2)));
typedef float    v4f __attribute__((ext_vector_type(4)));
typedef unsigned v4u __attribute__((ext_vector_type(4)));

// ---- ws layout (32-bit word offsets) ----
#define OFF_FLAGS_E 0          // 256 u32, contiguous
#define OFF_FLAGS_D 256        // 256 u32
#define OFF_HBUF_E  512        // 3*3072 f32  [slot][ e1 h (2048) | e2 h (1024) ]
#define OFF_HBUF_D  9728       // 3*3072 f32  [slot][ d1 h (1024) | d2 h (2048) ]
#define OFF_XG4     18944      // 3*6144 f32  d2 input gates, mod-3 slots
#define OFF_XGD1    37376      // 3072 f32    d1 constant input gates (incl bih)
#define OFF_PART    40448      // 128*4096 f32 per-wg output partials
#define INIT_WORDS  40448

#define DEV __device__ __forceinline__

DEV float sigm(float v){ return __fdividef(1.f, 1.f + __expf(-v)); }
DEV float tanhx(float v){ float e = __expf(2.f*v); return 1.f - __fdividef(2.f, e + 1.f); }

DEV float wred(float v){
  #pragma unroll
  for (int m = 32; m; m >>= 1) v += __shfl_xor(v, m, 64);
  return v;
}

// scalar agent-scope (bypass non-coherent L1/L2, data via L3)
DEV void  sstore(float* p, float v){ __hip_atomic_store(p, v, __ATOMIC_RELAXED, __HIP_MEMORY_SCOPE_AGENT); }

// vector scoped ops (sc0 sc1 = bypass L1/L2)
DEV v4f ldx4s(const float* p){
  v4f a;
  asm volatile("global_load_dwordx4 %0, %1, off sc0 sc1\n\ts_waitcnt vmcnt(0)"
               : "=v"(a) : "v"(p) : "memory");
  return a;
}
DEV v2f ldx2s(const float* p){
  v2f a;
  asm volatile("global_load_dwordx2 %0, %1, off sc0 sc1\n\ts_waitcnt vmcnt(0)"
               : "=v"(a) : "v"(p) : "memory");
  return a;
}
DEV v4u ldx4su(const unsigned* p){
  v4u a;
  asm volatile("global_load_dwordx4 %0, %1, off sc0 sc1\n\ts_waitcnt vmcnt(0)"
               : "=v"(a) : "v"(p) : "memory");
  return a;
}
DEV void stx4s(float* p, v4f v){
  asm volatile("global_store_dwordx4 %0, %1, off sc0 sc1" :: "v"(p), "v"(v) : "memory");
}

// force value into a VGPR at init (blocks remat/sink into the loop)
#define PINV(x) asm volatile("" : "+v"(x))

// Distributed 256-wg barrier: contiguous flags, wave 0 polls with dwordx4 sweep.
DEV void gbar(unsigned* flags, int wg, unsigned target, int tid){
  __syncthreads();                  // per-wave vmcnt drain: scoped stores committed
  if (tid == 0)
    __hip_atomic_store(&flags[wg], target, __ATOMIC_RELAXED, __HIP_MEMORY_SCOPE_AGENT);
  if (tid < 64){
    const unsigned* fp = flags + tid*4;
    for (;;){
      v4u v = ldx4su(fp);
      unsigned m0 = v.x < v.y ? v.x : v.y;
      unsigned m1 = v.z < v.w ? v.z : v.w;
      unsigned m  = m0 < m1 ? m0 : m1;
      if (__all(m >= target)) break;
      __builtin_amdgcn_s_sleep(2);
    }
  }
  __syncthreads();
}

__global__ void init_kernel(unsigned* ws){
  const int i = blockIdx.x*blockDim.x + threadIdx.x;
  if (i < INIT_WORDS) ws[i] = 0u;
}

// ============ ENCODER: e1 (128 wgs, 2 rows/wave) + e2 lag-1 (128 wgs, 1 row/wave) ============
__global__ __launch_bounds__(512, 1) __attribute__((amdgpu_waves_per_eu(2,2)))
void enc_kernel(
    const float* __restrict__ x,
    const float* __restrict__ e1_Wih, const float* __restrict__ e1_Whh,
    const float* __restrict__ e1_bih, const float* __restrict__ e1_bhh,
    const float* __restrict__ e2_Wih, const float* __restrict__ e2_Whh,
    const float* __restrict__ e2_bih, const float* __restrict__ e2_bhh,
    float* ws)
{
  const int wg = blockIdx.x, tid = threadIdx.x;
  const int wave = tid >> 6, lane = tid & 63;
  float* hbuf = ws + OFF_HBUF_E;
  unsigned* flags = (unsigned*)ws + OFF_FLAGS_E;

  __shared__ __align__(16) float sh[3072];
  __shared__ __align__(16) float sOut[16];
  __shared__ float sW[8][6], sBi[8][6], sBh[8][6];

  if (wg < 128){
    // ---- e1 (H=2048, K=2048). wave owns rows i0,i0+1; lane owns cols c*64+lane. ----
    const int gw = wg*8 + wave;          // 0..1023
    const int i0 = gw*2;
    float w[3][2][32];                   // 192 VGPRs
    #pragma unroll
    for (int g=0; g<3; ++g)
      #pragma unroll
      for (int j=0; j<2; ++j)
        #pragma unroll
        for (int c=0; c<32; ++c){
          w[g][j][c] = e1_Whh[(size_t)(g*2048 + i0 + j)*2048 + c*64 + lane];
          PINV(w[g][j][c]);
        }
    if (lane < 6){
      const int g = lane >> 1, j = lane & 1;
      const int row = g*2048 + i0 + j;
      sW[wave][lane]  = e1_Wih[row];
      sBi[wave][lane] = e1_bih[row];
      sBh[wave][lane] = e1_bhh[row];
    }
    __syncthreads();
    for (int s=0; s<=T_STEPS; ++s){
      if (s < T_STEPS){
        const int t = s;
        const float* hp = hbuf + ((t+2)%3)*3072;
        float*       hw = hbuf + (t%3)*3072;
        { v4f a = ldx4s(hp + tid*4); *(v4f*)&sh[tid*4] = a; }   // 2048 f32
        __syncthreads();
        float hpv[2];
        #pragma unroll
        for (int j=0;j<2;++j) hpv[j] = sh[i0+j];
        const float xt = x[t];
        float acc[3][2];
        #pragma unroll
        for (int g=0;g<3;++g){ acc[g][0]=0.f; acc[g][1]=0.f; }
        #pragma unroll
        for (int cc=0; cc<4; ++cc){
          float hh[8];
          #pragma unroll
          for (int u=0;u<8;++u) hh[u] = sh[(cc*8+u)*64 + lane];
          #pragma unroll
          for (int g=0; g<3; ++g)
            #pragma unroll
            for (int j=0; j<2; ++j)
              #pragma unroll
              for (int u=0;u<8;++u)
                acc[g][j] = __fmaf_rn(w[g][j][cc*8+u], hh[u], acc[g][j]);
        }
        #pragma unroll
        for (int j=0; j<2; ++j){
          const float hr = wred(acc[0][j]);
          const float hz = wred(acc[1][j]);
          const float hn = wred(acc[2][j]);
          const float r = sigm (__fmaf_rn(xt, sW[wave][j],   sBi[wave][j])   + hr + sBh[wave][j]);
          const float z = sigm (__fmaf_rn(xt, sW[wave][2+j], sBi[wave][2+j]) + hz + sBh[wave][2+j]);
          const float n = tanhx(__fmaf_rn(xt, sW[wave][4+j], sBi[wave][4+j]) + r*(hn + sBh[wave][4+j]));
          const float hnew = (1.f - z)*n + z*hpv[j];
          if (lane == 0) sOut[wave*2 + j] = hnew;
        }
        __syncthreads();
        if (tid == 0){   // packed publication: block rows wg*16..+15
          stx4s(hw + wg*16,      *(v4f*)&sOut[0]);
          stx4s(hw + wg*16 + 4,  *(v4f*)&sOut[4]);
          stx4s(hw + wg*16 + 8,  *(v4f*)&sOut[8]);
          stx4s(hw + wg*16 + 12, *(v4f*)&sOut[12]);
        }
      }
      gbar(flags, wg, (unsigned)(s+1), tid);
    }
  } else {
    // ---- e2 (H=1024, Kin=2048, Khh=1024) lag-1. wave owns row i0. ----
    const int gw = (wg-128)*8 + wave;    // 0..1023
    const int i0 = gw;
    float wih[3][32], whh[3][16];        // 144 VGPRs
    #pragma unroll
    for (int g=0; g<3; ++g){
      #pragma unroll
      for (int c=0; c<32; ++c){
        wih[g][c] = e2_Wih[(size_t)(g*1024 + i0)*2048 + c*64 + lane];
        PINV(wih[g][c]);
      }
      #pragma unroll
      for (int c=0; c<16; ++c){
        whh[g][c] = e2_Whh[(size_t)(g*1024 + i0)*1024 + c*64 + lane];
        PINV(whh[g][c]);
      }
    }
    if (lane < 3){
      const int row = lane*1024 + i0;
      sBi[wave][lane] = e2_bih[row];
      sBh[wave][lane] = e2_bhh[row];
    }
    __syncthreads();
    for (int s=0; s<=T_STEPS; ++s){
      if (s >= 1){
        const int t = s-1;
        const float* yp  = hbuf + (t%3)*3072;            // ys1[t]
        const float* hp2 = hbuf + ((t+2)%3)*3072 + 2048; // own h_{t-1}
        float*       hw  = hbuf + (t%3)*3072 + 2048;
        { v4f a = ldx4s(yp + tid*4);  *(v4f*)&sh[tid*4] = a; }        // 2048
        { v2f b = ldx2s(hp2 + tid*2); *(v2f*)&sh[2048 + tid*2] = b; } // 1024
        __syncthreads();
        const float hpv = sh[2048 + i0];
        float ar=0.f, az=0.f, axn=0.f, ahn=0.f;
        #pragma unroll
        for (int cc=0; cc<4; ++cc){
          float yy[8];
          #pragma unroll
          for (int u=0;u<8;++u) yy[u] = sh[(cc*8+u)*64 + lane];
          #pragma unroll
          for (int u=0;u<8;++u){
            ar  = __fmaf_rn(wih[0][cc*8+u], yy[u], ar);
            az  = __fmaf_rn(wih[1][cc*8+u], yy[u], az);
            axn = __fmaf_rn(wih[2][cc*8+u], yy[u], axn);
          }
        }
        #pragma unroll
        for (int cc=0; cc<2; ++cc){
          float hh[8];
          #pragma unroll
          for (int u=0;u<8;++u) hh[u] = sh[2048 + (cc*8+u)*64 + lane];
          #pragma unroll
          for (int u=0;u<8;++u){
            ar  = __fmaf_rn(whh[0][cc*8+u], hh[u], ar);
            az  = __fmaf_rn(whh[1][cc*8+u], hh[u], az);
            ahn = __fmaf_rn(whh[2][cc*8+u], hh[u], ahn);
          }
        }
        const float arr = wred(ar), azr = wred(az), axnr = wred(axn), ahnr = wred(ahn);
        const float r = sigm (arr + sBi[wave][0] + sBh[wave][0]);
        const float z = sigm (azr + sBi[wave][1] + sBh[wave][1]);
        const float n = tanhx(axnr + sBi[wave][2] + r*(ahnr + sBh[wave][2]));
        const float hnew = (1.f - z)*n + z*hpv;
        if (lane == 0) sOut[wave] = hnew;
        __syncthreads();
        if (tid == 0){   // block rows (wg-128)*8..+7
          stx4s(hw + (wg-128)*8,     *(v4f*)&sOut[0]);
          stx4s(hw + (wg-128)*8 + 4, *(v4f*)&sOut[4]);
        }
      }
      gbar(flags, wg, (unsigned)(s+1), tid);
    }
  }
}

// xgd1[row] = d1_Wih[row,:] . hT + d1_bih[row]  (hT = e2 h at t=4095, slot 0)
__global__ void xgd1_kernel(const float* __restrict__ d1_Wih,
                            const float* __restrict__ d1_bih, float* ws){
  const int gw = blockIdx.x*4 + (threadIdx.x >> 6);  // row 0..3071
  const int lane = threadIdx.x & 63;
  const float* hT = ws + OFF_HBUF_E + 2048;          // slot 0, e2 section
  float a = 0.f;
  #pragma unroll
  for (int c=0;c<16;++c)
    a = __fmaf_rn(d1_Wih[(size_t)gw*1024 + c*64 + lane], hT[c*64 + lane], a);
  a = wred(a);
  if (lane == 0) ws[OFF_XGD1 + gw] = a + d1_bih[gw];
}

// ====== DECODER: d1 (64 wgs, 2 rows/wave) + d2-gemv lag-1 (64 wgs, 12 rows/wave)
//                + d2 lag-2 (128 wgs, 2 rows/wave) ======
__global__ __launch_bounds__(512, 1) __attribute__((amdgpu_waves_per_eu(2,2)))
void dec_kernel(
    const float* __restrict__ d1_Whh, const float* __restrict__ d1_bhh,
    const float* __restrict__ d2_Wih, const float* __restrict__ d2_Whh,
    const float* __restrict__ d2_bih, const float* __restrict__ d2_bhh,
    const float* __restrict__ out_W,
    float* ws)
{
  const int wg = blockIdx.x, tid = threadIdx.x;
  const int wave = tid >> 6, lane = tid & 63;
  float* hbuf = ws + OFF_HBUF_D;
  float* xg4  = ws + OFF_XG4;
  unsigned* flags = (unsigned*)ws + OFF_FLAGS_D;
  __shared__ __align__(16) float sh[2048];
  __shared__ __align__(16) float sOut[16];
  __shared__ float sPS[8];

  if (wg < 64){
    // ---- d1 (H=1024, K=1024), constant input gates. wave owns rows i0,i0+1. ----
    const int gw = wg*8 + wave;       // 0..511
    const int i0 = gw*2;
    float w[3][2][16];                // 96 VGPRs
    #pragma unroll
    for (int g=0; g<3; ++g)
      #pragma unroll
      for (int j=0; j<2; ++j)
        #pragma unroll
        for (int c=0; c<16; ++c){
          w[g][j][c] = d1_Whh[(size_t)(g*1024 + i0 + j)*1024 + c*64 + lane];
          PINV(w[g][j][c]);
        }
    float cr[2], cz[2], cxn[2], cbn[2];
    const float* xgc = ws + OFF_XGD1;
    #pragma unroll
    for (int j=0; j<2; ++j){
      cr[j]  = xgc[i0+j]      + d1_bhh[i0+j];
      cz[j]  = xgc[1024+i0+j] + d1_bhh[1024+i0+j];
      cxn[j] = xgc[2048+i0+j];
      cbn[j] = d1_bhh[2048+i0+j];
    }
    for (int s=0; s<=T_STEPS+1; ++s){
      if (s < T_STEPS){
        const int t = s;
        const float* hp = hbuf + ((t+2)%3)*3072;
        float*       hw = hbuf + (t%3)*3072;
        { v2f a = ldx2s(hp + tid*2); *(v2f*)&sh[tid*2] = a; }  // 1024
        __syncthreads();
        float hpv[2];
        #pragma unroll
        for (int j=0;j<2;++j) hpv[j] = sh[i0+j];
        float a0[2]={0,0}, a1[2]={0,0}, a2[2]={0,0};
        #pragma unroll
        for (int cc=0; cc<2; ++cc){
          float hh[8];
          #pragma unroll
          for (int u=0;u<8;++u) hh[u] = sh[(cc*8+u)*64 + lane];
          #pragma unroll
          for (int j=0;j<2;++j)
            #pragma unroll
            for (int u=0;u<8;++u){
              a0[j] = __fmaf_rn(w[0][j][cc*8+u], hh[u], a0[j]);
              a1[j] = __fmaf_rn(w[1][j][cc*8+u], hh[u], a1[j]);
              a2[j] = __fmaf_rn(w[2][j][cc*8+u], hh[u], a2[j]);
            }
        }
        #pragma unroll
        for (int j=0; j<2; ++j){
          const float hr = wred(a0[j]), hz = wred(a1[j]), hn = wred(a2[j]);
          const float r = sigm (cr[j] + hr);
          const float z = sigm (cz[j] + hz);
          const float n = tanhx(cxn[j] + r*(hn + cbn[j]));
          const float hnew = (1.f - z)*n + z*hpv[j];
          if (lane == 0) sOut[wave*2 + j] = hnew;
        }
        __syncthreads();
        if (tid == 0){   // block rows wg*16..+15
          stx4s(hw + wg*16,      *(v4f*)&sOut[0]);
          stx4s(hw + wg*16 + 4,  *(v4f*)&sOut[4]);
          stx4s(hw + wg*16 + 8,  *(v4f*)&sOut[8]);
          stx4s(hw + wg*16 + 12, *(v4f*)&sOut[12]);
        }
      }
      gbar(flags, wg, (unsigned)(s+1), tid);
    }
  } else if (wg < 128){
    // ---- d2 input GEMV: xg4[t] = d2_Wih @ ys2[t] + bih, lag-1. wave owns 12 rows. ----
    const int gw = (wg-64)*8 + wave;   // 0..511
    const int r0 = gw*12;
    float w[12][16];                   // 192 VGPRs
    #pragma unroll
    for (int r=0; r<12; ++r)
      #pragma unroll
      for (int c=0; c<16; ++c){
        w[r][c] = d2_Wih[(size_t)(r0 + r)*1024 + c*64 + lane];
        PINV(w[r][c]);
      }
    float bv[12];
    #pragma unroll
    for (int r=0; r<12; ++r) bv[r] = d2_bih[r0+r];
    for (int s=0; s<=T_STEPS+1; ++s){
      if (s >= 1 && s <= T_STEPS){
        const int t = s-1;
        const float* yp = hbuf + (t%3)*3072;   // ys2[t] (d1 section)
        float*       xw = xg4 + (t%3)*6144;
        { v2f a = ldx2s(yp + tid*2); *(v2f*)&sh[tid*2] = a; }  // 1024
        __syncthreads();
        float acc[12];
        #pragma unroll
        for (int r=0;r<12;++r) acc[r]=0.f;
        #pragma unroll
        for (int cc=0; cc<4; ++cc){
          float yy[4];
          #pragma unroll
          for (int u=0;u<4;++u) yy[u] = sh[(cc*4+u)*64 + lane];
          #pragma unroll
          for (int r=0;r<12;++r)
            #pragma unroll
            for (int u=0;u<4;++u)
              acc[r] = __fmaf_rn(w[r][cc*4+u], yy[u], acc[r]);
        }
        float xv[12];
        #pragma unroll
        for (int r=0; r<12; ++r) xv[r] = wred(acc[r]) + bv[r];  // uniform in all lanes
        if (lane == 0){                 // packed: rows r0..r0+11
          v4f p0 = {xv[0], xv[1], xv[2],  xv[3]};
          v4f p1 = {xv[4], xv[5], xv[6],  xv[7]};
          v4f p2 = {xv[8], xv[9], xv[10], xv[11]};
          stx4s(xw + r0,     p0);
          stx4s(xw + r0 + 4, p1);
          stx4s(xw + r0 + 8, p2);
        }
      }
      gbar(flags, wg, (unsigned)(s+1), tid);
    }
  } else {
    // ---- d2 (H=2048, K=2048) lag-2, fused output projection. wave owns rows i0,i0+1. ----
    const int gw = (wg-128)*8 + wave;  // 0..1023
    const int i0 = gw*2;
    float w[3][2][32];                 // 192 VGPRs
    #pragma unroll
    for (int g=0; g<3; ++g)
      #pragma unroll
      for (int j=0; j<2; ++j)
        #pragma unroll
        for (int c=0; c<32; ++c){
          w[g][j][c] = d2_Whh[(size_t)(g*2048 + i0 + j)*2048 + c*64 + lane];
          PINV(w[g][j][c]);
        }
    float bh[3][2];
    #pragma unroll
    for (int g=0; g<3; ++g)
      #pragma unroll
      for (int j=0; j<2; ++j) bh[g][j] = d2_bhh[g*2048 + i0 + j];
    float ow[2];
    #pragma unroll
    for (int j=0; j<2; ++j) ow[j] = out_W[i0+j];
    float* part = ws + OFF_PART + (size_t)(wg-128)*4096;
    for (int s=0; s<=T_STEPS+1; ++s){
      if (s >= 2){
        const int t = s-2;
        const float* hp  = hbuf + ((t+2)%3)*3072 + 1024;
        float*       hw  = hbuf + (t%3)*3072 + 1024;
        const float* xgp = xg4 + (t%3)*6144;
        { v4f a = ldx4s(hp + tid*4); *(v4f*)&sh[tid*4] = a; }  // 2048
        __syncthreads();
        float hpv[2];
        v2f xr2 = ldx2s(xgp + i0);
        v2f xz2 = ldx2s(xgp + 2048 + i0);
        v2f xn2 = ldx2s(xgp + 4096 + i0);
        #pragma unroll
        for (int j=0;j<2;++j) hpv[j] = sh[i0+j];
        float a0[2]={0,0}, a1[2]={0,0}, a2[2]={0,0};
        #pragma unroll
        for (int cc=0; cc<4; ++cc){
          float hh[8];
          #pragma unroll
          for (int u=0;u<8;++u) hh[u] = sh[(cc*8+u)*64 + lane];
          #pragma unroll
          for (int j=0;j<2;++j)
            #pragma unroll
            for (int u=0;u<8;++u){
              a0[j] = __fmaf_rn(w[0][j][cc*8+u], hh[u], a0[j]);
              a1[j] = __fmaf_rn(w[1][j][cc*8+u], hh[u], a1[j]);
              a2[j] = __fmaf_rn(w[2][j][cc*8+u], hh[u], a2[j]);
            }
        }
        float op = 0.f;
        #pragma unroll
        for (int j=0; j<2; ++j){
          const float hr = wred(a0[j]), hz = wred(a1[j]), hn = wred(a2[j]);
          const float xr = j ? xr2.y : xr2.x;
          const float xz = j ? xz2.y : xz2.x;
          const float xn = j ? xn2.y : xn2.x;
          const float r = sigm (xr + hr + bh[0][j]);
          const float z = sigm (xz + hz + bh[1][j]);
          const float n = tanhx(xn + r*(hn + bh[2][j]));
          const float hnew = (1.f - z)*n + z*hpv[j];
          if (lane == 0) sOut[wave*2 + j] = hnew;
          op = __fmaf_rn(hnew, ow[j], op);
        }
        if (lane == 0) sPS[wave] = op;
        __syncthreads();
        if (tid == 0){   // block rows (wg-128)*16..+15 (within d2 section)
          const int base = (wg-128)*16;
          stx4s(hw + base,      *(v4f*)&sOut[0]);
          stx4s(hw + base + 4,  *(v4f*)&sOut[4]);
          stx4s(hw + base + 8,  *(v4f*)&sOut[8]);
          stx4s(hw + base + 12, *(v4f*)&sOut[12]);
          float ps = 0.f;
          #pragma unroll
          for (int v=0; v<8; ++v) ps += sPS[v];
          part[t] = ps;
        }
      }
      gbar(flags, wg, (unsigned)(s+1), tid);
    }
  }
}

__global__ void out_kernel(const float* __restrict__ out_b,
                           const float* __restrict__ ws, float* __restrict__ out){
  const int t = blockIdx.x*256 + threadIdx.x;
  float a = 0.f;
  for (int b=0; b<128; ++b) a += ws[OFF_PART + (size_t)b*4096 + t];
  out[t] = a + out_b[0];
}

extern "C" void kernel_launch(void* const* d_in, const int* in_sizes, int n_in,
                              void* d_out, int out_size, void* d_ws, size_t ws_size,
                              hipStream_t stream){
  const float* x       = (const float*)d_in[0];
  const float* e1_Wih  = (const float*)d_in[1];
  const float* e1_Whh  = (const float*)d_in[2];
  const float* e1_bih  = (const float*)d_in[3];
  const float* e1_bhh  = (const float*)d_in[4];
  const float* e2_Wih  = (const float*)d_in[5];
  const float* e2_Whh  = (const float*)d_in[6];
  const float* e2_bih  = (const float*)d_in[7];
  const float* e2_bhh  = (const float*)d_in[8];
  const float* d1_Wih  = (const float*)d_in[9];
  const float* d1_Whh  = (const float*)d_in[10];
  const float* d1_bih  = (const float*)d_in[11];
  const float* d1_bhh  = (const float*)d_in[12];
  const float* d2_Wih  = (const float*)d_in[13];
  const float* d2_Whh  = (const float*)d_in[14];
  const float* d2_bih  = (const float*)d_in[15];
  const float* d2_bhh  = (const float*)d_in[16];
  const float* out_W   = (const float*)d_in[17];
  const float* out_b   = (const float*)d_in[18];
  float* ws  = (float*)d_ws;
  float* out = (float*)d_out;

  hipLaunchKernelGGL(init_kernel, dim3((INIT_WORDS+255)/256), dim3(256), 0, stream,
                     (unsigned*)d_ws);
  hipLaunchKernelGGL(enc_kernel, dim3(256), dim3(512), 0, stream,
                     x, e1_Wih, e1_Whh, e1_bih, e1_bhh,
                     e2_Wih, e2_Whh, e2_bih, e2_bhh, ws);
  hipLaunchKernelGGL(xgd1_kernel, dim3(768), dim3(256), 0, stream,
                     d1_Wih, d1_bih, ws);
  hipLaunchKernelGGL(dec_kernel, dim3(256), dim3(512), 0, stream,
                     d1_Whh, d1_bhh, d2_Wih, d2_Whh, d2_bih, d2_bhh, out_W, ws);
  hipLaunchKernelGGL(out_kernel, dim3(16), dim3(256), 0, stream,
                     out_b, ws, out);
}